// Round 6
// baseline (170.522 us; speedup 1.0000x reference)
//
#include <hip/hip_runtime.h>

// Problem constants (from reference)
#define BATCH 16
#define NENT  512
#define D_IN  256
#define D_OUT 32
#define CSP   64
#define COUT  96        // 64 spatial + 32 scatter channels
#define HWDIM 256
#define HWSZ  65536     // 256*256
#define HW4   16384     // HWSZ/4  (2^14)
#define SP_B4  (CSP * HW4)    // 2^20 float4: spatial part per batch
#define SC_B4  (D_OUT * HW4)  // 2^19 float4: scatter part per batch
#define OUT_B4 (COUT * HW4)   // float4 per batch in out

// K1: zero ONLY the owner cells this call will touch (<=8192 of them).
// Untouched cells keep stale garbage but are never read. Multiple entities
// hitting the same cell all store 0 — benign race.
__global__ void zero_cells_kernel(const int* __restrict__ loc,
                                  int* __restrict__ owner) {
    int gid = blockIdx.x * blockDim.x + threadIdx.x;   // 0 .. 8191
    if (gid >= BATCH * NENT) return;
    int h = min(max(loc[gid * 2 + 0], 0), HWDIM - 1);
    int w = min(max(loc[gid * 2 + 1], 0), HWDIM - 1);
    int b = gid >> 9;
    owner[b * HWSZ + h * HWDIM + w] = 0;
}

// K2: last-write-wins resolution. owner[b, flat] = max(n+1).
__global__ void owner_kernel(const int* __restrict__ loc,
                             int* __restrict__ owner) {
    int gid = blockIdx.x * blockDim.x + threadIdx.x;   // 0 .. 8191
    if (gid >= BATCH * NENT) return;
    int h = min(max(loc[gid * 2 + 0], 0), HWDIM - 1);
    int w = min(max(loc[gid * 2 + 1], 0), HWDIM - 1);
    int b = gid >> 9;
    int n = gid & (NENT - 1);
    atomicMax(&owner[b * HWSZ + h * HWDIM + w], n + 1);
}

// K3: THE big pass — zero data dependencies, branch-free, 3 linear quanta
// per thread: 2 float4 copies + 1 zero store. grid = (2048, BATCH).
__global__ void bigpass_kernel(const float4* __restrict__ sp,
                               float4* __restrict__ out) {
    const int PER = 2048 * 256;                        // 524,288 threads/batch
    int b = blockIdx.y;
    int t = blockIdx.x * blockDim.x + threadIdx.x;
    const float4* spb  = sp  + (size_t)b * SP_B4;
    float4*       outb = out + (size_t)b * OUT_B4;
    outb[t]            = spb[t];                       // copy channels 0..31
    outb[t + PER]      = spb[t + PER];                 // copy channels 32..63
    outb[SP_B4 + t]    = make_float4(0.f, 0.f, 0.f, 0.f); // zero scatter chans
}

// K4: projection + winner scatter. Thread = (entity, e). emb row loaded as
// float4 (broadcast within each 32-lane group); Wp column reads coalesce
// across the 32 e-lanes and are L1-resident (32 KB total).
__global__ void proj_scatter_kernel(const float* __restrict__ emb,
                                    const float* __restrict__ Wp,
                                    const float* __restrict__ bp,
                                    const int* __restrict__ loc,
                                    const int* __restrict__ owner,
                                    float* __restrict__ out) {
    int gid = blockIdx.x * blockDim.x + threadIdx.x;   // 0 .. 262,143
    int ent = gid >> 5;          // entity index 0..8191
    int e   = gid & 31;          // output feature 0..31
    int b   = ent >> 9;
    int n   = ent & (NENT - 1);

    int h = min(max(loc[ent * 2 + 0], 0), HWDIM - 1);
    int w = min(max(loc[ent * 2 + 1], 0), HWDIM - 1);
    int flat = h * HWDIM + w;

    if (owner[b * HWSZ + flat] != n + 1) return;   // lost to a later entity

    const float4* er4 = (const float4*)(emb + (size_t)ent * D_IN);
    float acc = bp[e];
    #pragma unroll 8
    for (int d4 = 0; d4 < D_IN / 4; ++d4) {
        float4 ev = er4[d4];
        int d = d4 * 4;
        acc += ev.x * Wp[(d + 0) * D_OUT + e];
        acc += ev.y * Wp[(d + 1) * D_OUT + e];
        acc += ev.z * Wp[(d + 2) * D_OUT + e];
        acc += ev.w * Wp[(d + 3) * D_OUT + e];
    }
    out[(size_t)b * (COUT * HWSZ) + (CSP + e) * HWSZ + flat] = acc;
}

extern "C" void kernel_launch(void* const* d_in, const int* in_sizes, int n_in,
                              void* d_out, int out_size, void* d_ws, size_t ws_size,
                              hipStream_t stream) {
    const float* spatial = (const float*)d_in[0];   // [16,64,256,256]
    const float* emb     = (const float*)d_in[1];   // [16,512,256]
    const float* Wp      = (const float*)d_in[2];   // [256,32]
    const float* bp      = (const float*)d_in[3];   // [32]
    const int*   loc     = (const int*)d_in[4];     // [16,512,2]
    float* out = (float*)d_out;                     // [16,96,256,256]
    int* owner = (int*)d_ws;                        // 4 MB (only cells touched
                                                    //  by loc are ever used)

    // 1: zero the owner cells this call touches
    zero_cells_kernel<<<32, 256, 0, stream>>>(loc, owner);
    // 2: resolve duplicate locations (last write wins)
    owner_kernel<<<32, 256, 0, stream>>>(loc, owner);
    // 3: dependency-free bulk pass (copy 64 ch + zero 32 ch)
    dim3 grid(2048, BATCH);
    bigpass_kernel<<<grid, 256, 0, stream>>>((const float4*)spatial,
                                             (float4*)out);
    // 4: project + scatter winners directly into out
    proj_scatter_kernel<<<1024, 256, 0, stream>>>(emb, Wp, bp, loc, owner, out);
}

// Round 9
// 137.100 us; speedup vs baseline: 1.2438x; 1.2438x over previous
//
#include <hip/hip_runtime.h>

// Problem constants (from reference)
#define BATCH 16
#define NENT  512
#define D_IN  256
#define D_OUT 32
#define CSP   64
#define COUT  96        // 64 spatial + 32 scatter channels
#define HWDIM 256
#define HWSZ  65536     // 256*256
#define HW4   16384     // HWSZ/4  (2^14)
#define SP_B4  (CSP * HW4)    // 2^20 float4: spatial part per batch
#define SC_B4  (D_OUT * HW4)  // 2^19 float4: scatter part per batch
#define OUT_B4 (COUT * HW4)   // float4 per batch in out

// clang-native 16B vector type (accepted by __builtin_nontemporal_*)
typedef float vfloat4 __attribute__((ext_vector_type(4)));
typedef int   vint4   __attribute__((ext_vector_type(4)));

// K_A: zero owner[] (int4) AND compute proj[b,n,e] into ws.
// 2048 blocks x 256: first 262144 threads zero, rest project with float4
// emb loads (broadcast within each 32-lane group; Wp coalesced + L1-hot).
__global__ void init_proj_kernel(const float* __restrict__ emb,
                                 const float* __restrict__ Wp,
                                 const float* __restrict__ bp,
                                 vint4* __restrict__ owner4,
                                 float* __restrict__ projbuf) {
    int tid = blockIdx.x * blockDim.x + threadIdx.x;
    const int NZ4 = BATCH * HWSZ / 4;              // 262,144 int4 zeros
    if (tid < NZ4) {
        vint4 z = {0, 0, 0, 0};
        owner4[tid] = z;
        return;
    }
    int gid = tid - NZ4;                           // 0 .. 262,143
    int ent = gid >> 5;                            // entity 0..8191
    int e   = gid & 31;                            // feature 0..31
    const vfloat4* er4 = (const vfloat4*)(emb + (size_t)ent * D_IN);
    float acc = bp[e];
    #pragma unroll 8
    for (int d4 = 0; d4 < D_IN / 4; ++d4) {
        vfloat4 ev = er4[d4];
        int d = d4 * 4;
        acc += ev.x * Wp[(d + 0) * D_OUT + e];
        acc += ev.y * Wp[(d + 1) * D_OUT + e];
        acc += ev.z * Wp[(d + 2) * D_OUT + e];
        acc += ev.w * Wp[(d + 3) * D_OUT + e];
    }
    projbuf[gid] = acc;                            // coalesced
}

// K_B: last-write-wins resolution. owner[b, flat] = max(n+1).
__global__ void owner_kernel(const int* __restrict__ loc,
                             int* __restrict__ owner) {
    int gid = blockIdx.x * blockDim.x + threadIdx.x;   // 0 .. 8191
    if (gid >= BATCH * NENT) return;
    int h = min(max(loc[gid * 2 + 0], 0), HWDIM - 1);
    int w = min(max(loc[gid * 2 + 1], 0), HWDIM - 1);
    int b = gid >> 9;
    int n = gid & (NENT - 1);
    atomicMax(&owner[b * HWSZ + h * HWDIM + w], n + 1);
}

// K_C: single linear pass over the output (R4 structure). grid=(2048,BATCH).
// iter 0/1: nontemporal float4 copy; iter 2: scatter fill, nontemporal store,
// cached owner/projbuf gathers (those have real L2 reuse).
__global__ void fused_out_kernel(const vfloat4* __restrict__ sp,
                                 const vint4* __restrict__ owner4,
                                 const float* __restrict__ projbuf,
                                 vfloat4* __restrict__ out) {
    const int PER = 2048 * 256;                        // 524,288 per batch
    int b = blockIdx.y;
    int t = blockIdx.x * blockDim.x + threadIdx.x;     // 0 .. PER-1

    const vfloat4* spb  = sp  + (size_t)b * SP_B4;
    vfloat4*       outb = out + (size_t)b * OUT_B4;

    // two pure linear copy quanta (2^20 float4 = 64 channels), streaming
    vfloat4 c0 = __builtin_nontemporal_load(&spb[t]);
    __builtin_nontemporal_store(c0, &outb[t]);
    vfloat4 c1 = __builtin_nontemporal_load(&spb[t + PER]);
    __builtin_nontemporal_store(c1, &outb[t + PER]);

    // scatter quantum: t covers 2^19 float4 = 32 channels x HW4
    int e   = t >> 14;                                 // channel 0..31
    int hw4 = t & (HW4 - 1);
    vint4 ow = owner4[b * HW4 + hw4];                  // shared by 32 e-threads
    const float* pb = projbuf + b * (NENT * D_OUT) + e;
    // speculative loads with clamped index (no exec-mask branches)
    float vx = pb[max(ow.x - 1, 0) * D_OUT];
    float vy = pb[max(ow.y - 1, 0) * D_OUT];
    float vz = pb[max(ow.z - 1, 0) * D_OUT];
    float vw = pb[max(ow.w - 1, 0) * D_OUT];
    vfloat4 v;
    v.x = ow.x ? vx : 0.f;
    v.y = ow.y ? vy : 0.f;
    v.z = ow.z ? vz : 0.f;
    v.w = ow.w ? vw : 0.f;
    __builtin_nontemporal_store(v, &outb[SP_B4 + t]);
}

extern "C" void kernel_launch(void* const* d_in, const int* in_sizes, int n_in,
                              void* d_out, int out_size, void* d_ws, size_t ws_size,
                              hipStream_t stream) {
    const float* spatial = (const float*)d_in[0];   // [16,64,256,256]
    const float* emb     = (const float*)d_in[1];   // [16,512,256]
    const float* Wp      = (const float*)d_in[2];   // [256,32]
    const float* bp      = (const float*)d_in[3];   // [32]
    const int*   loc     = (const int*)d_in[4];     // [16,512,2]
    float* out = (float*)d_out;                     // [16,96,256,256]

    int*   owner   = (int*)d_ws;                                         // 4 MB
    float* projbuf = (float*)((char*)d_ws + BATCH * HWSZ * sizeof(int)); // 1 MB

    // A: zero owner + compute proj (independent work, one launch)
    init_proj_kernel<<<2048, 256, 0, stream>>>(emb, Wp, bp, (vint4*)owner, projbuf);
    // B: resolve duplicate locations (last write wins)
    owner_kernel<<<32, 256, 0, stream>>>(loc, owner);
    // C: single linear pass writing all 96 output channels
    dim3 grid(2048, BATCH);
    fused_out_kernel<<<grid, 256, 0, stream>>>((const vfloat4*)spatial,
                                               (const vint4*)owner, projbuf,
                                               (vfloat4*)out);
}